// Round 3
// baseline (906.106 us; speedup 1.0000x reference)
//
#include <hip/hip_runtime.h>
#include <cfloat>
#include <climits>

// Problem constants
#define N_ROWS 65536          // 64*1024 flattened rows
#define DIM 256
#define K_CODES 1024
#define N_ELEM 16777216       // N_ROWS*DIM
#define OUT_LOSS_OFF 16777216
#define OUT_IDX_OFF  16777217

// Tiling for the argmin kernel
#define ROWS_PER_BLOCK 128
#define CODES_PER_TILE 128
#define DC 32                 // d-chunk staged in LDS
#define LDS_STRIDE 36         // 32 + 4 pad
// Ref computes dists in fp32 with the +||x||^2 (~256) term -> grid ulp ~3.05e-5.
// Quantized-vs-exact per-code differential error <= 2*ulp ~ 6.2e-5. Flag margin
// below 1.5e-4 (2.4x safety) and re-evaluate those rows in ref-emulated arithmetic.
#define EPS_MARGIN 1.5e-4f

// ws layout (bytes)
#define WS_PARTIALS 0         // 1024 double
#define WS_ESQ      8192      // 1024 float
#define WS_IDX      12288     // 65536 int
#define WS_FLAGCNT  274432    // 1 int
#define WS_FLAGLIST 274436    // up to 65536 int

// ---- numpy fp32 pairwise sum-of-squares over 256 elements ----
// numpy: n=256 -> recurse into 128+128; each 128 uses the 8-accumulator
// unrolled loop; combine ((r0+r1)+(r2+r3)) + ((r4+r5)+(r6+r7)); halves added.
// Squares are rounded to fp32 BEFORE summation (flat*flat is a materialized
// fp32 array) -> __fmul_rn/__fadd_rn to forbid FMA contraction.
__device__ __forceinline__ float np_pairwise_sumsq(const float* __restrict__ a) {
    float half[2];
    #pragma unroll
    for (int h = 0; h < 2; ++h) {
        const float* p = a + h * 128;
        float r[8];
        #pragma unroll
        for (int j = 0; j < 8; ++j) r[j] = __fmul_rn(p[j], p[j]);
        for (int i = 8; i < 128; i += 8) {
            #pragma unroll
            for (int j = 0; j < 8; ++j)
                r[j] = __fadd_rn(r[j], __fmul_rn(p[i + j], p[i + j]));
        }
        half[h] = __fadd_rn(__fadd_rn(__fadd_rn(r[0], r[1]), __fadd_rn(r[2], r[3])),
                            __fadd_rn(__fadd_rn(r[4], r[5]), __fadd_rn(r[6], r[7])));
    }
    return __fadd_rn(half[0], half[1]);
}

// ---------------- Kernel E: per-code squared norms (numpy-order fp32) --------
__global__ void esq_kernel(const float* __restrict__ e, float* __restrict__ esq) {
    int c = blockIdx.x * 256 + threadIdx.x;
    if (c < K_CODES) esq[c] = np_pairwise_sumsq(e + c * DIM);
}

// ---------------- Kernel A: fp32 distance + argmin (top-2 tracked) ----------------
__launch_bounds__(256, 2)
__global__ void argmin_kernel(const float* __restrict__ x, const float* __restrict__ e,
                              const float* __restrict__ esq, int* __restrict__ wsIdx,
                              int* __restrict__ flagCnt, int* __restrict__ flagList) {
    __shared__ float xs[ROWS_PER_BLOCK * LDS_STRIDE];   // 4608 floats
    __shared__ float es[CODES_PER_TILE * LDS_STRIDE];   // 4608 floats
    __shared__ float esq_s[CODES_PER_TILE];

    const int t = threadIdx.x;
    const int tr = t >> 4;       // 0..15 -> row group
    const int tc = t & 15;       // 0..15 -> code group
    const int rowBase = blockIdx.x * ROWS_PER_BLOCK;

    float bv[8], sv[8];
    int bi[8];
    #pragma unroll
    for (int i = 0; i < 8; ++i) { bv[i] = FLT_MAX; sv[i] = FLT_MAX; bi[i] = INT_MAX; }

    const float4* x4 = (const float4*)x;
    const float4* e4 = (const float4*)e;

    for (int kt = 0; kt < K_CODES / CODES_PER_TILE; ++kt) {
        const int ktBase = kt * CODES_PER_TILE;
        float acc[8][8];
        #pragma unroll
        for (int i = 0; i < 8; ++i)
            #pragma unroll
            for (int j = 0; j < 8; ++j) acc[i][j] = 0.0f;

        for (int dc = 0; dc < DIM / DC; ++dc) {
            __syncthreads();
            #pragma unroll
            for (int q = 0; q < 4; ++q) {
                int f4id = t + 256 * q;          // 0..1023
                int r = f4id >> 3;               // row/code 0..127
                int c4 = f4id & 7;               // float4 col within chunk
                float4 xvv = x4[(rowBase + r) * 64 + dc * 8 + c4];
                float4 evv = e4[(ktBase + r) * 64 + dc * 8 + c4];
                *(float4*)&xs[r * LDS_STRIDE + c4 * 4] = xvv;
                *(float4*)&es[r * LDS_STRIDE + c4 * 4] = evv;
            }
            if (dc == 0 && t < CODES_PER_TILE) esq_s[t] = esq[ktBase + t];
            __syncthreads();

            #pragma unroll
            for (int d = 0; d < DC; d += 4) {
                float4 xv[8], ev[8];
                #pragma unroll
                for (int i = 0; i < 8; ++i)
                    xv[i] = *(const float4*)&xs[(tr + 16 * i) * LDS_STRIDE + d];
                #pragma unroll
                for (int j = 0; j < 8; ++j)
                    ev[j] = *(const float4*)&es[(tc + 16 * j) * LDS_STRIDE + d];
                #pragma unroll
                for (int i = 0; i < 8; ++i)
                    #pragma unroll
                    for (int j = 0; j < 8; ++j) {
                        acc[i][j] = fmaf(xv[i].x, ev[j].x, acc[i][j]);
                        acc[i][j] = fmaf(xv[i].y, ev[j].y, acc[i][j]);
                        acc[i][j] = fmaf(xv[i].z, ev[j].z, acc[i][j]);
                        acc[i][j] = fmaf(xv[i].w, ev[j].w, acc[i][j]);
                    }
            }
        }

        // epilogue: s = ||e||^2 - 2*dot (row-constant ||x||^2 omitted: same argmin,
        // better precision). Per-thread top-2; c strictly increasing -> strict '<'
        // keeps lowest index on ties.
        #pragma unroll
        for (int j = 0; j < 8; ++j) {
            float cs = esq_s[tc + 16 * j];
            int c = ktBase + tc + 16 * j;
            #pragma unroll
            for (int i = 0; i < 8; ++i) {
                float s = fmaf(-2.0f, acc[i][j], cs);
                if (s < bv[i]) {
                    sv[i] = bv[i]; bv[i] = s; bi[i] = c;
                } else if (s < sv[i]) {
                    sv[i] = s;
                }
            }
        }
    }

    // ---- cross-lane top-2 merge via LDS (reuses xs/es) ----
    __syncthreads();
    float* bvA = xs;              // [128 rows][16 lanes]
    int*   biA = (int*)(xs + 2048);
    float* svA = es;
    #pragma unroll
    for (int i = 0; i < 8; ++i) {
        int slot = (tr + 16 * i) * 16 + tc;
        bvA[slot] = bv[i];
        biA[slot] = bi[i];
        svA[slot] = sv[i];
    }
    __syncthreads();

    if (t < ROWS_PER_BLOCK) {
        float bb = FLT_MAX, ss = FLT_MAX;
        int ii = INT_MAX;
        for (int k = 0; k < 16; ++k) {
            float v  = bvA[t * 16 + k];
            int   id = biA[t * 16 + k];
            float s2 = svA[t * 16 + k];
            if (v < bb || (v == bb && id < ii)) {
                ss = fminf(bb, s2);
                bb = v; ii = id;
            } else {
                ss = fminf(ss, v);
            }
        }
        int row = rowBase + t;
        wsIdx[row] = ii;
        if (ss - bb < EPS_MARGIN) {   // quantization could flip: ref-emulated rescore
            int p = atomicAdd(flagCnt, 1);
            flagList[p] = row;
        }
    }
}

// ------- Kernel A2: reference-emulated fp32-quantized rescore of flagged rows -------
// Emulates numpy: s = fl32( fl32(A_r + B_c) - 2*fl32(dot_rc) ), argmin first-index.
// dot in fp64 (vs BLAS sgemm: differs ~1e-9, flips only on ~1e-7-probability
// grid-boundary straddles). A_r, B_c in numpy pairwise fp32 order.
__global__ void rescore_kernel(const float* __restrict__ x, const float* __restrict__ e,
                               const float* __restrict__ esq, int* __restrict__ wsIdx,
                               const int* __restrict__ flagCnt, const int* __restrict__ flagList) {
    __shared__ __align__(16) float xsh[DIM];
    __shared__ float Ash;
    __shared__ float rv[256];
    __shared__ int ri[256];
    const int t = threadIdx.x;
    const int cnt = *flagCnt;
    for (int w = blockIdx.x; w < cnt; w += gridDim.x) {
        const int row = flagList[w];
        __syncthreads();
        xsh[t] = x[row * DIM + t];
        __syncthreads();
        if (t == 0) Ash = np_pairwise_sumsq(xsh);
        __syncthreads();
        const float A = Ash;

        float bb = FLT_MAX;
        int ii = INT_MAX;
        #pragma unroll
        for (int c0 = 0; c0 < K_CODES; c0 += 256) {
            int c = c0 + t;
            const float4* ec4 = (const float4*)(e + c * DIM);
            const float4* xc4 = (const float4*)xsh;
            double dot = 0.0;
            #pragma unroll 8
            for (int d4 = 0; d4 < 64; ++d4) {
                float4 ev = ec4[d4];
                float4 xv = xc4[d4];
                dot += (double)ev.x * (double)xv.x + (double)ev.y * (double)xv.y
                     + (double)ev.z * (double)xv.z + (double)ev.w * (double)xv.w;
            }
            float M = (float)dot;                              // fl32(matmul)
            float s = __fsub_rn(__fadd_rn(A, esq[c]),          // fl32(A+B) then
                                __fmul_rn(2.0f, M));           // fl32(.. - 2M)
            if (s < bb || (s == bb && c < ii)) { bb = s; ii = c; }
        }
        rv[t] = bb; ri[t] = ii;
        __syncthreads();
        for (int off = 128; off > 0; off >>= 1) {
            if (t < off) {
                if (rv[t + off] < rv[t] || (rv[t + off] == rv[t] && ri[t + off] < ri[t])) {
                    rv[t] = rv[t + off]; ri[t] = ri[t + off];
                }
            }
            __syncthreads();
        }
        if (t == 0) wsIdx[row] = ri[0];
        __syncthreads();
    }
}

// ---------------- Kernel B: gather quantized + SSE partials + indices-as-float ----------------
__global__ void gather_kernel(const float* __restrict__ x, const float* __restrict__ e,
                              const int* __restrict__ wsIdx, float* __restrict__ out,
                              double* __restrict__ partials) {
    const float4* x4 = (const float4*)x;
    const float4* e4 = (const float4*)e;
    float4* q4 = (float4*)out;
    float* outIdx = out + OUT_IDX_OFF;
    const int tid = blockIdx.x * 256 + threadIdx.x;   // 0..262143
    double sse = 0.0;
    #pragma unroll 4
    for (int i = 0; i < 16; ++i) {
        int u = tid + i * 262144;      // float4 unit, 0..4194303
        int row = u >> 6;
        int c4 = u & 63;
        int idx = wsIdx[row];
        float4 q = e4[idx * 64 + c4];
        float4 xv = x4[u];
        q4[u] = q;
        double dx = (double)q.x - (double)xv.x;
        double dy = (double)q.y - (double)xv.y;
        double dz = (double)q.z - (double)xv.z;
        double dw = (double)q.w - (double)xv.w;
        sse += dx * dx + dy * dy + dz * dz + dw * dw;
    }
    if (tid < N_ROWS) outIdx[tid] = (float)wsIdx[tid];
    #pragma unroll
    for (int m = 1; m < 64; m <<= 1) sse += __shfl_xor(sse, m);
    __shared__ double wsum[4];
    if ((threadIdx.x & 63) == 0) wsum[threadIdx.x >> 6] = sse;
    __syncthreads();
    if (threadIdx.x == 0)
        partials[blockIdx.x] = wsum[0] + wsum[1] + wsum[2] + wsum[3];
}

// ---------------- Kernel C: final loss reduce ----------------
__global__ void loss_kernel(const double* __restrict__ partials, float* __restrict__ out) {
    __shared__ double sh[256];
    const int t = threadIdx.x;
    double s = partials[t] + partials[t + 256] + partials[t + 512] + partials[t + 768];
    sh[t] = s;
    __syncthreads();
    for (int off = 128; off > 0; off >>= 1) {
        if (t < off) sh[t] += sh[t + off];
        __syncthreads();
    }
    if (t == 0) out[OUT_LOSS_OFF] = (float)(0.25 * sh[0] / (double)N_ELEM);
}

extern "C" void kernel_launch(void* const* d_in, const int* in_sizes, int n_in,
                              void* d_out, int out_size, void* d_ws, size_t ws_size,
                              hipStream_t stream) {
    (void)in_sizes; (void)n_in; (void)out_size; (void)ws_size;
    const float* x = (const float*)d_in[0];
    const float* e = (const float*)d_in[1];
    float* out = (float*)d_out;
    char* ws = (char*)d_ws;
    double* partials = (double*)(ws + WS_PARTIALS);
    float* esq = (float*)(ws + WS_ESQ);
    int* wsIdx = (int*)(ws + WS_IDX);
    int* flagCnt = (int*)(ws + WS_FLAGCNT);
    int* flagList = (int*)(ws + WS_FLAGLIST);

    hipMemsetAsync(flagCnt, 0, sizeof(int), stream);
    esq_kernel<<<4, 256, 0, stream>>>(e, esq);
    argmin_kernel<<<N_ROWS / ROWS_PER_BLOCK, 256, 0, stream>>>(x, e, esq, wsIdx, flagCnt, flagList);
    rescore_kernel<<<512, 256, 0, stream>>>(x, e, esq, wsIdx, flagCnt, flagList);
    gather_kernel<<<1024, 256, 0, stream>>>(x, e, wsIdx, out, partials);
    loss_kernel<<<1, 256, 0, stream>>>(partials, out);
}

// Round 4
// 403.566 us; speedup vs baseline: 2.2452x; 2.2452x over previous
//
#include <hip/hip_runtime.h>
#include <cfloat>
#include <climits>

// Problem constants
#define N_ROWS 65536          // 64*1024 flattened rows
#define DIM 256
#define K_CODES 1024
#define N_ELEM 16777216       // N_ROWS*DIM
#define OUT_LOSS_OFF 16777216
#define OUT_IDX_OFF  16777217

#define ROWS_PB 128           // rows per block (argmin)
#define CT 128                // codes per tile
#define BK 64                 // k-chunk staged in LDS
// Ref computes dists in fp32 with +||x||^2 (~256) -> grid ulp ~3.05e-5; flips
// need exact gap <= ~6.5e-5. Pass-1 (bf16-split MFMA) error ~2e-6. Margin
// 1.5e-4 keeps >2x safety. Proven in round 3 - do not change semantics.
#define EPS_MARGIN 1.5e-4f
#define SHORTLIST_EPS 6e-4f   // >= 2*2e-4 (ehi-only dot err) + 6.5e-5 + slack

// ws layout (bytes)
#define WS_PARTIALS 0         // 1024 double
#define WS_ESQ      8192      // 1024 float
#define WS_IDX      12288     // 65536 int
#define WS_FLAGCNT  274432    // 1 int
#define WS_FLAGLIST 274436    // up to 65536 int -> ends 536580
#define WS_EHI      540672    // 1024*256 u16 = 512 KB
#define WS_ELO      1064960   // 512 KB -> ends 1589248

typedef unsigned short u16;
typedef __attribute__((ext_vector_type(8))) short bf16x8;
typedef __attribute__((ext_vector_type(4))) float f32x4;

// ---- exact two-term bf16 split (RN) ----
__device__ __forceinline__ void bsplit(float x, u16& h, u16& l) {
    unsigned u = __float_as_uint(x);
    unsigned hb = (u + 0x7fffu + ((u >> 16) & 1u)) >> 16;
    h = (u16)hb;
    float hf = __uint_as_float(hb << 16);
    float lf = x - hf;                       // exact
    unsigned u2 = __float_as_uint(lf);
    l = (u16)((u2 + 0x7fffu + ((u2 >> 16) & 1u)) >> 16);
}

// ---- numpy fp32 pairwise sum-of-squares over 256 elements (round-3 proven) ----
__device__ __forceinline__ float np_pairwise_sumsq(const float* __restrict__ a) {
    float half[2];
    #pragma unroll
    for (int h = 0; h < 2; ++h) {
        const float* p = a + h * 128;
        float r[8];
        #pragma unroll
        for (int j = 0; j < 8; ++j) r[j] = __fmul_rn(p[j], p[j]);
        for (int i = 8; i < 128; i += 8) {
            #pragma unroll
            for (int j = 0; j < 8; ++j)
                r[j] = __fadd_rn(r[j], __fmul_rn(p[i + j], p[i + j]));
        }
        half[h] = __fadd_rn(__fadd_rn(__fadd_rn(r[0], r[1]), __fadd_rn(r[2], r[3])),
                            __fadd_rn(__fadd_rn(r[4], r[5]), __fadd_rn(r[6], r[7])));
    }
    return __fadd_rn(half[0], half[1]);
}

// ---------------- prep: split x and e into bf16 hi/lo ----------------
__global__ void xsplit_kernel(const float* __restrict__ x, u16* __restrict__ xhi,
                              u16* __restrict__ xlo) {
    int i4 = blockIdx.x * 256 + threadIdx.x;       // 0..4194303
    float4 v = ((const float4*)x)[i4];
    ushort4 h, l;
    bsplit(v.x, h.x, l.x); bsplit(v.y, h.y, l.y);
    bsplit(v.z, h.z, l.z); bsplit(v.w, h.w, l.w);
    ((ushort4*)xhi)[i4] = h;
    ((ushort4*)xlo)[i4] = l;
}

__global__ void esplit_kernel(const float* __restrict__ e, u16* __restrict__ ehi,
                              u16* __restrict__ elo) {
    int i4 = blockIdx.x * 256 + threadIdx.x;       // 0..65535
    float4 v = ((const float4*)e)[i4];
    ushort4 h, l;
    bsplit(v.x, h.x, l.x); bsplit(v.y, h.y, l.y);
    bsplit(v.z, h.z, l.z); bsplit(v.w, h.w, l.w);
    ((ushort4*)ehi)[i4] = h;
    ((ushort4*)elo)[i4] = l;
}

// ---------------- per-code squared norms (numpy-order fp32, round-3 proven) ----
__global__ void esq_kernel(const float* __restrict__ e, float* __restrict__ esq) {
    int c = blockIdx.x * 256 + threadIdx.x;
    if (c < K_CODES) esq[c] = np_pairwise_sumsq(e + c * DIM);
}

// ---------------- Kernel A: split-bf16 MFMA distance + argmin ----------------
// Block: 128 rows x all 1024 codes, 4 waves in 2x2 (each wave 64 rows x 64 codes).
// LDS tiles [128][BK=64] u16, 16B-blocks XOR-swizzled by row&7 to spread banks.
__launch_bounds__(256, 2)
__global__ void argmin_kernel(const u16* __restrict__ xhi, const u16* __restrict__ xlo,
                              const u16* __restrict__ ehi, const u16* __restrict__ elo,
                              const float* __restrict__ esq, int* __restrict__ wsIdx,
                              int* __restrict__ flagCnt, int* __restrict__ flagList) {
    __shared__ __align__(16) unsigned char lds[65536];
    __shared__ float esq_s[CT];
    u16* xhiS = (u16*)lds;              // [128][64] swizzled, 16 KB
    u16* xloS = (u16*)(lds + 16384);
    u16* ehiS = (u16*)(lds + 32768);
    u16* eloS = (u16*)(lds + 49152);

    const int t = threadIdx.x;
    const int w = t >> 6;               // wave 0..3
    const int l = t & 63;
    const int lane15 = l & 15;
    const int quad = l >> 4;            // 0..3
    const int rowBase = blockIdx.x * ROWS_PB;
    const int waveRowOff = (w >> 1) * 64;
    const int waveColOff = (w & 1) * 64;

    // per-thread top-2 per row-slot (16 rows/lane), over its 32 candidate codes
    float bv[16], sv[16]; int bi[16];
    #pragma unroll
    for (int i = 0; i < 16; ++i) { bv[i] = FLT_MAX; sv[i] = FLT_MAX; bi[i] = INT_MAX; }

    // staging role: wave w copies array w
    const u16* src; u16* dst; int gIsX;
    if (w == 0)      { src = xhi; dst = xhiS; gIsX = 1; }
    else if (w == 1) { src = xlo; dst = xloS; gIsX = 1; }
    else if (w == 2) { src = ehi; dst = ehiS; gIsX = 0; }
    else             { src = elo; dst = eloS; gIsX = 0; }
    const int sub = l >> 3;             // row-in-group-of-8
    const int jb = l & 7;               // 16B-block slot
    const int sb = jb ^ sub;            // swizzled source block (r&7 == sub)

    for (int ct = 0; ct < 8; ++ct) {
        const int ctBase = ct * CT;
        __syncthreads();                          // prior epilogue/LDS reads done
        if (t < CT) esq_s[t] = esq[ctBase + t];

        f32x4 acc[4][4];
        #pragma unroll
        for (int ti = 0; ti < 4; ++ti)
            #pragma unroll
            for (int tj = 0; tj < 4; ++tj) acc[ti][tj] = (f32x4){0.f, 0.f, 0.f, 0.f};

        for (int ch = 0; ch < 4; ++ch) {
            __syncthreads();
            // stage 16 KB: rows r = i*8+sub; logical k-block sb -> physical slot jb
            const int gRowBase = gIsX ? rowBase : ctBase;
            #pragma unroll
            for (int i = 0; i < 16; ++i) {
                int r = i * 8 + sub;
                uint4 v = *(const uint4*)(src + (size_t)(gRowBase + r) * 256 + ch * 64 + sb * 8);
                *(uint4*)(dst + r * 64 + jb * 8) = v;
            }
            __syncthreads();

            #pragma unroll
            for (int kk = 0; kk < 2; ++kk) {      // two 32-wide k-steps
                bf16x8 ah[4], al4[4], bh[4], bl[4];
                const int blk = kk * 4 + quad;    // 16B-block index in row
                #pragma unroll
                for (int ti = 0; ti < 4; ++ti) {
                    int r = waveRowOff + ti * 16 + lane15;
                    int off = r * 64 + ((blk ^ (r & 7)) * 8);
                    ah[ti]  = *(const bf16x8*)(xhiS + off);
                    al4[ti] = *(const bf16x8*)(xloS + off);
                }
                #pragma unroll
                for (int tj = 0; tj < 4; ++tj) {
                    int r = waveColOff + tj * 16 + lane15;
                    int off = r * 64 + ((blk ^ (r & 7)) * 8);
                    bh[tj] = *(const bf16x8*)(ehiS + off);
                    bl[tj] = *(const bf16x8*)(eloS + off);
                }
                #pragma unroll
                for (int ti = 0; ti < 4; ++ti)
                    #pragma unroll
                    for (int tj = 0; tj < 4; ++tj) {
                        acc[ti][tj] = __builtin_amdgcn_mfma_f32_16x16x32_bf16(al4[ti], bh[tj], acc[ti][tj], 0, 0, 0);
                        acc[ti][tj] = __builtin_amdgcn_mfma_f32_16x16x32_bf16(ah[ti], bl[tj], acc[ti][tj], 0, 0, 0);
                        acc[ti][tj] = __builtin_amdgcn_mfma_f32_16x16x32_bf16(ah[ti], bh[tj], acc[ti][tj], 0, 0, 0);
                    }
            }
        }

        // epilogue: s = ||e||^2 - 2*dot. D-layout: row(M)=quad*4+reg, col(N)=lane&15.
        #pragma unroll
        for (int tj = 0; tj < 4; ++tj) {
            int cLoc = waveColOff + tj * 16 + lane15;
            float cs = esq_s[cLoc];
            int c = ctBase + cLoc;
            #pragma unroll
            for (int ti = 0; ti < 4; ++ti)
                #pragma unroll
                for (int r4 = 0; r4 < 4; ++r4) {
                    int slot = ti * 4 + r4;
                    float s = fmaf(-2.0f, acc[ti][tj][r4], cs);
                    if (s < bv[slot]) {           // candidates ascend in c -> '<' keeps lowest idx
                        sv[slot] = bv[slot]; bv[slot] = s; bi[slot] = c;
                    } else if (s < sv[slot]) {
                        sv[slot] = s;
                    }
                }
        }
    }

    // ---- final cross-contributor top-2 merge via LDS (reuses tile memory) ----
    __syncthreads();
    float* bvA = (float*)lds;                     // [128 rows][32 contributors]
    float* svA = (float*)(lds + 16384);
    int*   biA = (int*)(lds + 32768);
    const int contrib = (w & 1) * 16 + lane15;    // 0..31
    #pragma unroll
    for (int slot = 0; slot < 16; ++slot) {
        int m = waveRowOff + (slot >> 2) * 16 + quad * 4 + (slot & 3);
        bvA[m * 32 + contrib] = bv[slot];
        svA[m * 32 + contrib] = sv[slot];
        biA[m * 32 + contrib] = bi[slot];
    }
    __syncthreads();

    if (t < ROWS_PB) {
        float bb = FLT_MAX, ss = FLT_MAX;
        int ii = INT_MAX;
        for (int k = 0; k < 32; ++k) {
            float v  = bvA[t * 32 + k];
            int   id = biA[t * 32 + k];
            float s2 = svA[t * 32 + k];
            if (v < bb || (v == bb && id < ii)) {
                ss = fminf(bb, s2);
                bb = v; ii = id;
            } else {
                ss = fminf(ss, v);
            }
        }
        int row = rowBase + t;
        wsIdx[row] = ii;
        if (ss - bb < EPS_MARGIN) {
            int p = atomicAdd(flagCnt, 1);
            flagList[p] = row;
        }
    }
}

// ------- Kernel A2: flagged-row rescore -------
// Phase A: bf16-hi fp32 scores over all 1024 codes -> shortlist within 6e-4 of min
// (superset of possible quantized winners). Phase B: numpy-emulated quantized
// score (round-3 proven formula) on shortlist; lexicographic (s, idx) argmin.
__global__ void rescore_kernel(const float* __restrict__ x, const float* __restrict__ e,
                               const u16* __restrict__ ehi, const float* __restrict__ esq,
                               int* __restrict__ wsIdx, const int* __restrict__ flagCnt,
                               const int* __restrict__ flagList) {
    __shared__ __align__(16) float xsh[DIM];
    __shared__ float Ash;
    __shared__ float minsh[256];
    __shared__ int scnt;
    __shared__ int slist[64];
    __shared__ float sres[64];
    const int t = threadIdx.x;
    const int cnt = *flagCnt;
    for (int w = blockIdx.x; w < cnt; w += gridDim.x) {
        const int row = flagList[w];
        __syncthreads();
        xsh[t] = x[row * DIM + t];
        if (t == 0) scnt = 0;
        __syncthreads();
        if (t == 0) Ash = np_pairwise_sumsq(xsh);

        // phase A: 4 codes/thread, dot(x, ehi) in fp32 (err <= ~2e-4)
        float sA[4]; int cA[4];
        float mymin = FLT_MAX;
        #pragma unroll
        for (int j = 0; j < 4; ++j) {
            int c = j * 256 + t;
            const uint4* ep = (const uint4*)(ehi + (size_t)c * DIM);
            float dot = 0.f;
            for (int q = 0; q < 32; ++q) {
                uint4 uv = ep[q];
                const float* xp = xsh + q * 8;
                dot = fmaf(__uint_as_float(uv.x << 16),        xp[0], dot);
                dot = fmaf(__uint_as_float(uv.x & 0xffff0000u), xp[1], dot);
                dot = fmaf(__uint_as_float(uv.y << 16),        xp[2], dot);
                dot = fmaf(__uint_as_float(uv.y & 0xffff0000u), xp[3], dot);
                dot = fmaf(__uint_as_float(uv.z << 16),        xp[4], dot);
                dot = fmaf(__uint_as_float(uv.z & 0xffff0000u), xp[5], dot);
                dot = fmaf(__uint_as_float(uv.w << 16),        xp[6], dot);
                dot = fmaf(__uint_as_float(uv.w & 0xffff0000u), xp[7], dot);
            }
            float s = fmaf(-2.f, dot, esq[c]);
            sA[j] = s; cA[j] = c;
            mymin = fminf(mymin, s);
        }
        minsh[t] = mymin;
        __syncthreads();
        for (int off = 128; off > 0; off >>= 1) {
            if (t < off) minsh[t] = fminf(minsh[t], minsh[t + off]);
            __syncthreads();
        }
        float thr = minsh[0] + SHORTLIST_EPS;
        #pragma unroll
        for (int j = 0; j < 4; ++j) {
            if (sA[j] <= thr) {
                int p = atomicAdd(&scnt, 1);
                if (p < 64) slist[p] = cA[j];
            }
        }
        __syncthreads();
        int ns = scnt < 64 ? scnt : 64;
        const float A = Ash;
        if (t < ns) {
            int c = slist[t];
            const float4* ec4 = (const float4*)(e + (size_t)c * DIM);
            const float4* xc4 = (const float4*)xsh;
            double dot = 0.0;
            #pragma unroll 8
            for (int d4 = 0; d4 < 64; ++d4) {
                float4 ev = ec4[d4];
                float4 xv = xc4[d4];
                dot += (double)ev.x * (double)xv.x + (double)ev.y * (double)xv.y
                     + (double)ev.z * (double)xv.z + (double)ev.w * (double)xv.w;
            }
            float M = (float)dot;
            sres[t] = __fsub_rn(__fadd_rn(A, esq[c]), __fmul_rn(2.0f, M));
        }
        __syncthreads();
        if (t == 0) {
            float bb = FLT_MAX; int ii = INT_MAX;
            for (int k = 0; k < ns; ++k) {
                float s = sres[k]; int c = slist[k];
                if (s < bb || (s == bb && c < ii)) { bb = s; ii = c; }
            }
            wsIdx[row] = ii;
        }
        __syncthreads();
    }
}

// ---------------- Kernel B: gather quantized + SSE partials + indices-as-float ----------------
__global__ void gather_kernel(const float* __restrict__ x, const float* __restrict__ e,
                              const int* __restrict__ wsIdx, float* __restrict__ out,
                              double* __restrict__ partials) {
    const float4* x4 = (const float4*)x;
    const float4* e4 = (const float4*)e;
    float4* q4 = (float4*)out;
    float* outIdx = out + OUT_IDX_OFF;
    const int tid = blockIdx.x * 256 + threadIdx.x;   // 0..262143
    double sse = 0.0;
    #pragma unroll 4
    for (int i = 0; i < 16; ++i) {
        int u = tid + i * 262144;      // float4 unit, 0..4194303
        int row = u >> 6;
        int c4 = u & 63;
        int idx = wsIdx[row];
        float4 q = e4[idx * 64 + c4];
        float4 xv = x4[u];
        q4[u] = q;
        double dx = (double)q.x - (double)xv.x;
        double dy = (double)q.y - (double)xv.y;
        double dz = (double)q.z - (double)xv.z;
        double dw = (double)q.w - (double)xv.w;
        sse += dx * dx + dy * dy + dz * dz + dw * dw;
    }
    if (tid < N_ROWS) outIdx[tid] = (float)wsIdx[tid];
    #pragma unroll
    for (int m = 1; m < 64; m <<= 1) sse += __shfl_xor(sse, m);
    __shared__ double wsum[4];
    if ((threadIdx.x & 63) == 0) wsum[threadIdx.x >> 6] = sse;
    __syncthreads();
    if (threadIdx.x == 0)
        partials[blockIdx.x] = wsum[0] + wsum[1] + wsum[2] + wsum[3];
}

// ---------------- Kernel C: final loss reduce ----------------
__global__ void loss_kernel(const double* __restrict__ partials, float* __restrict__ out) {
    __shared__ double sh[256];
    const int t = threadIdx.x;
    double s = partials[t] + partials[t + 256] + partials[t + 512] + partials[t + 768];
    sh[t] = s;
    __syncthreads();
    for (int off = 128; off > 0; off >>= 1) {
        if (t < off) sh[t] += sh[t + off];
        __syncthreads();
    }
    if (t == 0) out[OUT_LOSS_OFF] = (float)(0.25 * sh[0] / (double)N_ELEM);
}

extern "C" void kernel_launch(void* const* d_in, const int* in_sizes, int n_in,
                              void* d_out, int out_size, void* d_ws, size_t ws_size,
                              hipStream_t stream) {
    (void)in_sizes; (void)n_in; (void)out_size; (void)ws_size;
    const float* x = (const float*)d_in[0];
    const float* e = (const float*)d_in[1];
    float* out = (float*)d_out;
    char* ws = (char*)d_ws;
    double* partials = (double*)(ws + WS_PARTIALS);
    float* esq = (float*)(ws + WS_ESQ);
    int* wsIdx = (int*)(ws + WS_IDX);
    int* flagCnt = (int*)(ws + WS_FLAGCNT);
    int* flagList = (int*)(ws + WS_FLAGLIST);
    u16* ehi = (u16*)(ws + WS_EHI);
    u16* elo = (u16*)(ws + WS_ELO);
    // x hi/lo scratch lives in d_out (67 MB); consumed by argmin, then
    // overwritten by gather (stream-ordered, safe).
    u16* xhi = (u16*)d_out;
    u16* xlo = xhi + N_ELEM;

    hipMemsetAsync(flagCnt, 0, sizeof(int), stream);
    xsplit_kernel<<<16384, 256, 0, stream>>>(x, xhi, xlo);
    esplit_kernel<<<256, 256, 0, stream>>>(e, ehi, elo);
    esq_kernel<<<4, 256, 0, stream>>>(e, esq);
    argmin_kernel<<<N_ROWS / ROWS_PB, 256, 0, stream>>>(xhi, xlo, ehi, elo, esq,
                                                        wsIdx, flagCnt, flagList);
    rescore_kernel<<<2048, 256, 0, stream>>>(x, e, ehi, esq, wsIdx, flagCnt, flagList);
    gather_kernel<<<1024, 256, 0, stream>>>(x, e, wsIdx, out, partials);
    loss_kernel<<<1, 256, 0, stream>>>(partials, out);
}

// Round 5
// 325.129 us; speedup vs baseline: 2.7869x; 1.2412x over previous
//
#include <hip/hip_runtime.h>
#include <cfloat>
#include <climits>

// Problem constants
#define N_ROWS 65536          // 64*1024 flattened rows
#define DIM 256
#define K_CODES 1024
#define N_ELEM 16777216       // N_ROWS*DIM
#define OUT_LOSS_OFF 16777216
#define OUT_IDX_OFF  16777217

#define ROWS_PB 128           // rows per block (argmin)
#define CT 128                // codes per tile
// Ref computes dists in fp32 with +||x||^2 (~256) -> grid ulp ~3.05e-5; flips
// need exact gap <= ~6.5e-5. Pass-1 (bf16-split MFMA) error ~2e-6. Margin
// 1.5e-4 keeps >2x safety. Proven in rounds 3-4 - do not change semantics.
#define EPS_MARGIN 1.5e-4f
#define SHORTLIST_EPS 6e-4f   // covers exact-gap 6.6e-5 + 2*max|x.elo| ~4.2e-4
#define RB 8                  // flagged rows batched per rescore block

// ws layout (bytes)
#define WS_PARTIALS 0         // 1024 double
#define WS_ESQ      8192      // 1024 float
#define WS_IDX      12288     // 65536 int
#define WS_FLAGCNT  274432    // 1 int
#define WS_FLAGLIST 274436    // up to 65536 int -> ends 536580
#define WS_EHI      540672    // 1024*256 u16 = 512 KB (row-major, for argmin)
#define WS_ELO      1064960   // 512 KB
#define WS_EHIT     1589248   // 512 KB q-major transpose (for rescore) -> ends 2113536

typedef unsigned short u16;
typedef __attribute__((ext_vector_type(8))) short bf16x8;
typedef __attribute__((ext_vector_type(4))) float f32x4;

// ---- async global->LDS 16B (wave-uniform LDS base + lane*16) ----
__device__ __forceinline__ void glds16(const u16* g, u16* l) {
    __builtin_amdgcn_global_load_lds(
        (const __attribute__((address_space(1))) unsigned int*)(const void*)g,
        (__attribute__((address_space(3))) unsigned int*)(void*)l,
        16, 0, 0);
}

// ---- exact two-term bf16 split (RN) ----
__device__ __forceinline__ void bsplit(float x, u16& h, u16& l) {
    unsigned u = __float_as_uint(x);
    unsigned hb = (u + 0x7fffu + ((u >> 16) & 1u)) >> 16;
    h = (u16)hb;
    float hf = __uint_as_float(hb << 16);
    float lf = x - hf;                       // exact
    unsigned u2 = __float_as_uint(lf);
    l = (u16)((u2 + 0x7fffu + ((u2 >> 16) & 1u)) >> 16);
}

// ---- numpy fp32 pairwise sum-of-squares over 256 elements (round-3 proven) ----
__device__ __forceinline__ float np_pairwise_sumsq(const float* __restrict__ a) {
    float half[2];
    #pragma unroll
    for (int h = 0; h < 2; ++h) {
        const float* p = a + h * 128;
        float r[8];
        #pragma unroll
        for (int j = 0; j < 8; ++j) r[j] = __fmul_rn(p[j], p[j]);
        for (int i = 8; i < 128; i += 8) {
            #pragma unroll
            for (int j = 0; j < 8; ++j)
                r[j] = __fadd_rn(r[j], __fmul_rn(p[i + j], p[i + j]));
        }
        half[h] = __fadd_rn(__fadd_rn(__fadd_rn(r[0], r[1]), __fadd_rn(r[2], r[3])),
                            __fadd_rn(__fadd_rn(r[4], r[5]), __fadd_rn(r[6], r[7])));
    }
    return __fadd_rn(half[0], half[1]);
}

// ---------------- prep: split x and e into bf16 hi/lo ----------------
__global__ void xsplit_kernel(const float* __restrict__ x, u16* __restrict__ xhi,
                              u16* __restrict__ xlo) {
    int i4 = blockIdx.x * 256 + threadIdx.x;       // 0..4194303
    float4 v = ((const float4*)x)[i4];
    ushort4 h, l;
    bsplit(v.x, h.x, l.x); bsplit(v.y, h.y, l.y);
    bsplit(v.z, h.z, l.z); bsplit(v.w, h.w, l.w);
    ((ushort4*)xhi)[i4] = h;
    ((ushort4*)xlo)[i4] = l;
}

// e split: row-major hi/lo (argmin staging) + q-major hi transpose (rescore).
// ehiT layout: [qid 0..31][code 0..1023][8 u16], qid = 16B-chunk of the dim axis.
__global__ void esplit_kernel(const float* __restrict__ e, u16* __restrict__ ehi,
                              u16* __restrict__ elo, u16* __restrict__ ehiT) {
    int i4 = blockIdx.x * 256 + threadIdx.x;       // 0..65535
    float4 v = ((const float4*)e)[i4];
    ushort4 h, l;
    bsplit(v.x, h.x, l.x); bsplit(v.y, h.y, l.y);
    bsplit(v.z, h.z, l.z); bsplit(v.w, h.w, l.w);
    ((ushort4*)ehi)[i4] = h;
    ((ushort4*)elo)[i4] = l;
    int c = i4 >> 6;
    int f4 = i4 & 63;
    int qid = f4 >> 1;
    ((ushort4*)ehiT)[((size_t)qid * 1024 + c) * 2 + (f4 & 1)] = h;
}

// ---------------- per-code squared norms (numpy-order fp32, round-3 proven) ----
__global__ void esq_kernel(const float* __restrict__ e, float* __restrict__ esq) {
    int c = blockIdx.x * 256 + threadIdx.x;
    if (c < K_CODES) esq[c] = np_pairwise_sumsq(e + c * DIM);
}

// ---------------- Kernel A: split-bf16 MFMA distance + argmin ----------------
// Block: 128 rows x all 1024 codes, 4 waves in 2x2 (each wave 64 rows x 64 codes).
// LDS tiles [128][64] u16, 16B-blocks XOR-swizzled by row&7; staging layout is
// lane-linear (byte off = i*1024 + lane*16) -> global_load_lds width 16.
__launch_bounds__(256, 2)
__global__ void argmin_kernel(const u16* __restrict__ xhi, const u16* __restrict__ xlo,
                              const u16* __restrict__ ehi, const u16* __restrict__ elo,
                              const float* __restrict__ esq, int* __restrict__ wsIdx,
                              int* __restrict__ flagCnt, int* __restrict__ flagList) {
    __shared__ __align__(16) unsigned char lds[65536];
    __shared__ float esq_s[CT];
    u16* xhiS = (u16*)lds;              // [128][64] swizzled, 16 KB
    u16* xloS = (u16*)(lds + 16384);
    u16* ehiS = (u16*)(lds + 32768);
    u16* eloS = (u16*)(lds + 49152);

    const int t = threadIdx.x;
    const int w = t >> 6;               // wave 0..3
    const int l = t & 63;
    const int lane15 = l & 15;
    const int quad = l >> 4;            // 0..3
    const int rowBase = blockIdx.x * ROWS_PB;
    const int waveRowOff = (w >> 1) * 64;
    const int waveColOff = (w & 1) * 64;

    float bv[16], sv[16]; int bi[16];
    #pragma unroll
    for (int i = 0; i < 16; ++i) { bv[i] = FLT_MAX; sv[i] = FLT_MAX; bi[i] = INT_MAX; }

    // staging role: wave w copies array w
    const u16* src; u16* dst; int gIsX;
    if (w == 0)      { src = xhi; dst = xhiS; gIsX = 1; }
    else if (w == 1) { src = xlo; dst = xloS; gIsX = 1; }
    else if (w == 2) { src = ehi; dst = ehiS; gIsX = 0; }
    else             { src = elo; dst = eloS; gIsX = 0; }
    const int sub = l >> 3;             // row-in-group-of-8
    const int jb = l & 7;               // 16B-block slot
    const int sb = jb ^ sub;            // swizzled source block

    for (int ct = 0; ct < 8; ++ct) {
        const int ctBase = ct * CT;
        __syncthreads();                          // prior epilogue/LDS reads done
        if (t < CT) esq_s[t] = esq[ctBase + t];

        f32x4 acc[4][4];
        #pragma unroll
        for (int ti = 0; ti < 4; ++ti)
            #pragma unroll
            for (int tj = 0; tj < 4; ++tj) acc[ti][tj] = (f32x4){0.f, 0.f, 0.f, 0.f};

        for (int ch = 0; ch < 4; ++ch) {
            __syncthreads();
            const int gRowBase = gIsX ? rowBase : ctBase;
            #pragma unroll
            for (int i = 0; i < 16; ++i) {
                int r = i * 8 + sub;
                glds16(src + (size_t)(gRowBase + r) * 256 + ch * 64 + sb * 8,
                       dst + i * 512);
            }
            __syncthreads();

            #pragma unroll
            for (int kk = 0; kk < 2; ++kk) {      // two 32-wide k-steps
                bf16x8 ah[4], al4[4], bh[4], bl[4];
                const int blk = kk * 4 + quad;    // 16B-block index in row
                #pragma unroll
                for (int ti = 0; ti < 4; ++ti) {
                    int r = waveRowOff + ti * 16 + lane15;
                    int off = r * 64 + ((blk ^ (r & 7)) * 8);
                    ah[ti]  = *(const bf16x8*)(xhiS + off);
                    al4[ti] = *(const bf16x8*)(xloS + off);
                }
                #pragma unroll
                for (int tj = 0; tj < 4; ++tj) {
                    int r = waveColOff + tj * 16 + lane15;
                    int off = r * 64 + ((blk ^ (r & 7)) * 8);
                    bh[tj] = *(const bf16x8*)(ehiS + off);
                    bl[tj] = *(const bf16x8*)(eloS + off);
                }
                #pragma unroll
                for (int ti = 0; ti < 4; ++ti)
                    #pragma unroll
                    for (int tj = 0; tj < 4; ++tj) {
                        acc[ti][tj] = __builtin_amdgcn_mfma_f32_16x16x32_bf16(al4[ti], bh[tj], acc[ti][tj], 0, 0, 0);
                        acc[ti][tj] = __builtin_amdgcn_mfma_f32_16x16x32_bf16(ah[ti], bl[tj], acc[ti][tj], 0, 0, 0);
                        acc[ti][tj] = __builtin_amdgcn_mfma_f32_16x16x32_bf16(ah[ti], bh[tj], acc[ti][tj], 0, 0, 0);
                    }
            }
        }

        // epilogue: s = ||e||^2 - 2*dot. D-layout: row(M)=quad*4+reg, col(N)=lane&15.
        #pragma unroll
        for (int tj = 0; tj < 4; ++tj) {
            int cLoc = waveColOff + tj * 16 + lane15;
            float cs = esq_s[cLoc];
            int c = ctBase + cLoc;
            #pragma unroll
            for (int ti = 0; ti < 4; ++ti)
                #pragma unroll
                for (int r4 = 0; r4 < 4; ++r4) {
                    int slot = ti * 4 + r4;
                    float s = fmaf(-2.0f, acc[ti][tj][r4], cs);
                    if (s < bv[slot]) {           // candidates ascend in c
                        sv[slot] = bv[slot]; bv[slot] = s; bi[slot] = c;
                    } else if (s < sv[slot]) {
                        sv[slot] = s;
                    }
                }
        }
    }

    // ---- final cross-contributor top-2 merge via LDS (reuses tile memory) ----
    __syncthreads();
    float* bvA = (float*)lds;                     // [128 rows][32 contributors]
    float* svA = (float*)(lds + 16384);
    int*   biA = (int*)(lds + 32768);
    const int contrib = (w & 1) * 16 + lane15;    // 0..31
    #pragma unroll
    for (int slot = 0; slot < 16; ++slot) {
        int m = waveRowOff + (slot >> 2) * 16 + quad * 4 + (slot & 3);
        bvA[m * 32 + contrib] = bv[slot];
        svA[m * 32 + contrib] = sv[slot];
        biA[m * 32 + contrib] = bi[slot];
    }
    __syncthreads();

    if (t < ROWS_PB) {
        float bb = FLT_MAX, ss = FLT_MAX;
        int ii = INT_MAX;
        for (int k = 0; k < 32; ++k) {
            float v  = bvA[t * 32 + k];
            int   id = biA[t * 32 + k];
            float s2 = svA[t * 32 + k];
            if (v < bb || (v == bb && id < ii)) {
                ss = fminf(bb, s2);
                bb = v; ii = id;
            } else {
                ss = fminf(ss, v);
            }
        }
        int row = rowBase + t;
        wsIdx[row] = ii;
        if (ss - bb < EPS_MARGIN) {
            int p = atomicAdd(flagCnt, 1);
            flagList[p] = row;
        }
    }
}

// ------- Kernel A2: flagged-row rescore, RB rows batched per block -------
// Phase A: bf16-hi fp32 scores over all 1024 codes via q-major ehiT
// (coalesced; each ehi byte read once per 8 rows) -> per-row shortlist within
// SHORTLIST_EPS of min. Phase B: numpy-emulated quantized score (round-3/4
// proven formula) on shortlist; lexicographic (s, idx) argmin.
__launch_bounds__(256)
__global__ void rescore_kernel(const float* __restrict__ x, const float* __restrict__ e,
                               const u16* __restrict__ ehiT, const float* __restrict__ esq,
                               int* __restrict__ wsIdx, const int* __restrict__ flagCnt,
                               const int* __restrict__ flagList) {
    __shared__ __align__(16) float xsh[RB][DIM];      // 8 KB
    __shared__ float Ash[RB];
    __shared__ float minsh[RB][256];                  // 8 KB
    __shared__ float thrsh[RB];
    __shared__ int scnt[RB];
    __shared__ int slist[RB][32];
    __shared__ float sres[RB][32];
    const int t = threadIdx.x;
    const int cnt = *flagCnt;
    const int ngroups = (cnt + RB - 1) / RB;
    for (int g = blockIdx.x; g < ngroups; g += gridDim.x) {
        const int base = g * RB;
        const int nr = (cnt - base < RB) ? (cnt - base) : RB;
        __syncthreads();                               // protect reuse across groups
        #pragma unroll
        for (int r = 0; r < RB; ++r)
            xsh[r][t] = (r < nr) ? x[(size_t)flagList[base + r] * DIM + t] : 0.0f;
        if (t < RB) scnt[t] = 0;
        __syncthreads();
        if (t < RB) Ash[t] = np_pairwise_sumsq(xsh[t]);

        // phase A: sA[j][r] = dot(x_r, ehi_c), c = j*256+t
        float sA[4][RB];
        #pragma unroll
        for (int j = 0; j < 4; ++j)
            #pragma unroll
            for (int r = 0; r < RB; ++r) sA[j][r] = 0.0f;

        const uint4* eT4 = (const uint4*)ehiT;
        for (int q = 0; q < 32; ++q) {
            float4 xq[RB][2];
            #pragma unroll
            for (int r = 0; r < RB; ++r) {             // broadcast LDS reads
                xq[r][0] = ((const float4*)xsh[r])[2 * q];
                xq[r][1] = ((const float4*)xsh[r])[2 * q + 1];
            }
            #pragma unroll
            for (int j = 0; j < 4; ++j) {
                uint4 uv = eT4[(size_t)q * 1024 + j * 256 + t];   // coalesced
                float e0 = __uint_as_float(uv.x << 16);
                float e1 = __uint_as_float(uv.x & 0xffff0000u);
                float e2 = __uint_as_float(uv.y << 16);
                float e3 = __uint_as_float(uv.y & 0xffff0000u);
                float e4v = __uint_as_float(uv.z << 16);
                float e5 = __uint_as_float(uv.z & 0xffff0000u);
                float e6 = __uint_as_float(uv.w << 16);
                float e7 = __uint_as_float(uv.w & 0xffff0000u);
                #pragma unroll
                for (int r = 0; r < RB; ++r) {
                    float d0 = sA[j][r];
                    d0 = fmaf(e0, xq[r][0].x, d0);
                    d0 = fmaf(e1, xq[r][0].y, d0);
                    d0 = fmaf(e2, xq[r][0].z, d0);
                    d0 = fmaf(e3, xq[r][0].w, d0);
                    d0 = fmaf(e4v, xq[r][1].x, d0);
                    d0 = fmaf(e5, xq[r][1].y, d0);
                    d0 = fmaf(e6, xq[r][1].z, d0);
                    d0 = fmaf(e7, xq[r][1].w, d0);
                    sA[j][r] = d0;
                }
            }
        }
        #pragma unroll
        for (int j = 0; j < 4; ++j) {
            float cs = esq[j * 256 + t];
            #pragma unroll
            for (int r = 0; r < RB; ++r)
                sA[j][r] = fmaf(-2.0f, sA[j][r], cs);
        }
        // per-row parallel min reduction
        #pragma unroll
        for (int r = 0; r < RB; ++r)
            minsh[r][t] = fminf(fminf(sA[0][r], sA[1][r]), fminf(sA[2][r], sA[3][r]));
        __syncthreads();
        for (int off = 128; off > 0; off >>= 1) {
            if (t < off) {
                #pragma unroll
                for (int r = 0; r < RB; ++r)
                    minsh[r][t] = fminf(minsh[r][t], minsh[r][t + off]);
            }
            __syncthreads();
        }
        if (t < RB) thrsh[t] = minsh[t][0] + SHORTLIST_EPS;
        __syncthreads();
        // shortlist build
        #pragma unroll
        for (int j = 0; j < 4; ++j)
            #pragma unroll
            for (int r = 0; r < RB; ++r)
                if (r < nr && sA[j][r] <= thrsh[r]) {
                    int p = atomicAdd(&scnt[r], 1);
                    if (p < 32) slist[r][p] = j * 256 + t;
                }
        __syncthreads();
        // phase B: thread -> (row r = t>>5, shortlist slot k = t&31)
        {
            int r = t >> 5, k = t & 31;
            int ns = scnt[r] < 32 ? scnt[r] : 32;
            if (r < nr && k < ns) {
                int c = slist[r][k];
                const float4* ec4 = (const float4*)(e + (size_t)c * DIM);
                const float4* xc4 = (const float4*)xsh[r];
                double dot = 0.0;
                #pragma unroll 8
                for (int d4 = 0; d4 < 64; ++d4) {
                    float4 ev = ec4[d4];
                    float4 xv = xc4[d4];
                    dot += (double)ev.x * (double)xv.x + (double)ev.y * (double)xv.y
                         + (double)ev.z * (double)xv.z + (double)ev.w * (double)xv.w;
                }
                float M = (float)dot;
                sres[r][k] = __fsub_rn(__fadd_rn(Ash[r], esq[c]), __fmul_rn(2.0f, M));
            }
        }
        __syncthreads();
        if (t < nr) {
            int ns = scnt[t] < 32 ? scnt[t] : 32;
            float bb = FLT_MAX; int ii = INT_MAX;
            for (int k = 0; k < ns; ++k) {
                float s = sres[t][k]; int c = slist[t][k];
                if (s < bb || (s == bb && c < ii)) { bb = s; ii = c; }
            }
            wsIdx[flagList[base + t]] = ii;
        }
    }
}

// ---------------- Kernel B: gather quantized + SSE partials + indices-as-float ----------------
__global__ void gather_kernel(const float* __restrict__ x, const float* __restrict__ e,
                              const int* __restrict__ wsIdx, float* __restrict__ out,
                              double* __restrict__ partials) {
    const float4* x4 = (const float4*)x;
    const float4* e4 = (const float4*)e;
    float4* q4 = (float4*)out;
    float* outIdx = out + OUT_IDX_OFF;
    const int tid = blockIdx.x * 256 + threadIdx.x;   // 0..262143
    double sse = 0.0;
    #pragma unroll 4
    for (int i = 0; i < 16; ++i) {
        int u = tid + i * 262144;      // float4 unit, 0..4194303
        int row = u >> 6;
        int c4 = u & 63;
        int idx = wsIdx[row];
        float4 q = e4[idx * 64 + c4];
        float4 xv = x4[u];
        q4[u] = q;
        double dx = (double)q.x - (double)xv.x;
        double dy = (double)q.y - (double)xv.y;
        double dz = (double)q.z - (double)xv.z;
        double dw = (double)q.w - (double)xv.w;
        sse += dx * dx + dy * dy + dz * dz + dw * dw;
    }
    if (tid < N_ROWS) outIdx[tid] = (float)wsIdx[tid];
    #pragma unroll
    for (int m = 1; m < 64; m <<= 1) sse += __shfl_xor(sse, m);
    __shared__ double wsum[4];
    if ((threadIdx.x & 63) == 0) wsum[threadIdx.x >> 6] = sse;
    __syncthreads();
    if (threadIdx.x == 0)
        partials[blockIdx.x] = wsum[0] + wsum[1] + wsum[2] + wsum[3];
}

// ---------------- Kernel C: final loss reduce ----------------
__global__ void loss_kernel(const double* __restrict__ partials, float* __restrict__ out) {
    __shared__ double sh[256];
    const int t = threadIdx.x;
    double s = partials[t] + partials[t + 256] + partials[t + 512] + partials[t + 768];
    sh[t] = s;
    __syncthreads();
    for (int off = 128; off > 0; off >>= 1) {
        if (t < off) sh[t] += sh[t + off];
        __syncthreads();
    }
    if (t == 0) out[OUT_LOSS_OFF] = (float)(0.25 * sh[0] / (double)N_ELEM);
}

extern "C" void kernel_launch(void* const* d_in, const int* in_sizes, int n_in,
                              void* d_out, int out_size, void* d_ws, size_t ws_size,
                              hipStream_t stream) {
    (void)in_sizes; (void)n_in; (void)out_size; (void)ws_size;
    const float* x = (const float*)d_in[0];
    const float* e = (const float*)d_in[1];
    float* out = (float*)d_out;
    char* ws = (char*)d_ws;
    double* partials = (double*)(ws + WS_PARTIALS);
    float* esq = (float*)(ws + WS_ESQ);
    int* wsIdx = (int*)(ws + WS_IDX);
    int* flagCnt = (int*)(ws + WS_FLAGCNT);
    int* flagList = (int*)(ws + WS_FLAGLIST);
    u16* ehi = (u16*)(ws + WS_EHI);
    u16* elo = (u16*)(ws + WS_ELO);
    u16* ehiT = (u16*)(ws + WS_EHIT);
    // x hi/lo scratch lives in d_out (67 MB); consumed by argmin/rescore, then
    // overwritten by gather (stream-ordered, safe).
    u16* xhi = (u16*)d_out;
    u16* xlo = xhi + N_ELEM;

    hipMemsetAsync(flagCnt, 0, sizeof(int), stream);
    xsplit_kernel<<<16384, 256, 0, stream>>>(x, xhi, xlo);
    esplit_kernel<<<256, 256, 0, stream>>>(e, ehi, elo, ehiT);
    esq_kernel<<<4, 256, 0, stream>>>(e, esq);
    argmin_kernel<<<N_ROWS / ROWS_PB, 256, 0, stream>>>(xhi, xlo, ehi, elo, esq,
                                                        wsIdx, flagCnt, flagList);
    rescore_kernel<<<512, 256, 0, stream>>>(x, e, ehiT, esq, wsIdx, flagCnt, flagList);
    gather_kernel<<<1024, 256, 0, stream>>>(x, e, wsIdx, out, partials);
    loss_kernel<<<1, 256, 0, stream>>>(partials, out);
}